// Round 3
// baseline (308.165 us; speedup 1.0000x reference)
//
#include <hip/hip_runtime.h>

#define BATCH 8
#define NN 10000      // nodes per graph
#define STB 512       // scatter block size
#define TB 256

__global__ void fx_kernel(const float* __restrict__ values,
                          float* __restrict__ fx, int bn) {
    int i = blockIdx.x * blockDim.x + threadIdx.x;
    if (i < bn) fx[i] = tanhf(values[i]);
}

// One block = (edge-chunk k, batch b). Accumulate w[e]*g[gather_idx] into an
// LDS array covering ALL N nodes, then flush partial sums (no global atomics).
// partial layout: partial[(k*BATCH+b)*N + i]
// chunk is a multiple of 4; e0 is 16B-aligned for int4/float4 loads.
__global__ __launch_bounds__(STB, 8) void scatter_lds_kernel(
        const float* __restrict__ gsrc,   // gather base [B*N] (fx or err)
        const float* __restrict__ w,      // [E]
        const int* __restrict__ idx,      // [2,E]
        float* __restrict__ partial,
        int E, int N, int chunk,
        long gather_off, long scatter_off)
{
    __shared__ float acc[NN];
    for (int i = threadIdx.x; i < N; i += STB) acc[i] = 0.0f;
    __syncthreads();

    const int k = blockIdx.x, b = blockIdx.y;
    const float* __restrict__ g = gsrc + (long)b * N;
    long e0 = (long)k * chunk;
    long e1 = e0 + chunk;
    if (e1 > E) e1 = E;
    long n = e1 - e0;
    long nvec = n >> 2;   // 4-edge groups

    const int*   gip = idx + gather_off + e0;
    const int*   sip = idx + scatter_off + e0;
    const float* wp  = w + e0;

    for (long v = threadIdx.x; v < nvec; v += STB) {
        int4   gi = ((const int4*)gip)[v];
        int4   si = ((const int4*)sip)[v];
        float4 wv = ((const float4*)wp)[v];
        // 4 independent gather+atomic chains in flight
        float m0 = wv.x * g[gi.x];
        float m1 = wv.y * g[gi.y];
        float m2 = wv.z * g[gi.z];
        float m3 = wv.w * g[gi.w];
        atomicAdd(&acc[si.x], m0);
        atomicAdd(&acc[si.y], m1);
        atomicAdd(&acc[si.z], m2);
        atomicAdd(&acc[si.w], m3);
    }
    // scalar tail
    for (long e = (nvec << 2) + threadIdx.x; e < n; e += STB) {
        atomicAdd(&acc[sip[e]], wp[e] * g[gip[e]]);
    }
    __syncthreads();

    float* __restrict__ p = partial + ((long)k * BATCH + b) * N;
    for (int i = threadIdx.x; i < N; i += STB) p[i] = acc[i];  // coalesced
}

// pred[j] = sum_k partial[k*BN+j];  err[j] = values[j] - pred[j]   (float4 over j)
__global__ void reduce_pred_err_kernel(const float4* __restrict__ partial,
                                       const float4* __restrict__ values,
                                       float4* __restrict__ pred,
                                       float4* __restrict__ err,
                                       int BN4, int K) {
    int j = blockIdx.x * blockDim.x + threadIdx.x;
    if (j >= BN4) return;
    float4 s = {0.f, 0.f, 0.f, 0.f};
    for (int k = 0; k < K; ++k) {
        float4 p = partial[(long)k * BN4 + j];
        s.x += p.x; s.y += p.y; s.z += p.z; s.w += p.w;
    }
    pred[j] = s;
    float4 v = values[j];
    float4 e = {v.x - s.x, v.y - s.y, v.z - s.z, v.w - s.w};
    err[j] = e;
}

// aggr[j] = sum_k partial[k*BN+j];  dx[j] = err[j] - (1-fx^2)*aggr
__global__ void reduce_dx_kernel(const float4* __restrict__ partial,
                                 const float4* __restrict__ fx,
                                 const float4* __restrict__ err,
                                 float4* __restrict__ dx,
                                 int BN4, int K) {
    int j = blockIdx.x * blockDim.x + threadIdx.x;
    if (j >= BN4) return;
    float4 s = {0.f, 0.f, 0.f, 0.f};
    for (int k = 0; k < K; ++k) {
        float4 p = partial[(long)k * BN4 + j];
        s.x += p.x; s.y += p.y; s.z += p.z; s.w += p.w;
    }
    float4 f = fx[j];
    float4 e = err[j];
    float4 d;
    d.x = e.x - (1.0f - f.x * f.x) * s.x;
    d.y = e.y - (1.0f - f.y * f.y) * s.y;
    d.z = e.z - (1.0f - f.z * f.z) * s.z;
    d.w = e.w - (1.0f - f.w * f.w) * s.w;
    dx[j] = d;
}

extern "C" void kernel_launch(void* const* d_in, const int* in_sizes, int n_in,
                              void* d_out, int out_size, void* d_ws, size_t ws_size,
                              hipStream_t stream) {
    const float* values  = (const float*)d_in[0];   // [B*N]
    const float* weights = (const float*)d_in[1];   // [E]
    const int*   edge_ix = (const int*)d_in[2];     // [2, E]

    const int BN = in_sizes[0];        // 80000
    const int E  = in_sizes[1];        // 2,000,000
    const int N  = BN / BATCH;         // 10000

    float* out  = (float*)d_out;       // [3, B*N]
    float* pred = out;
    float* err  = out + BN;
    float* dx   = out + 2 * BN;

    float* fx      = (float*)d_ws;               // BN floats
    float* partial = fx + BN;                    // K*BN floats

    // Pick K (edge chunks) to fit workspace; chunk multiple of 4 for alignment.
    size_t fx_bytes = (size_t)BN * sizeof(float);
    int K = 128;
    while (K > 8 && fx_bytes + (size_t)K * BN * sizeof(float) > ws_size) K >>= 1;
    int chunk = (((E + K - 1) / K) + 3) & ~3;
    int Kused = (E + chunk - 1) / chunk;

    fx_kernel<<<(BN + TB - 1) / TB, TB, 0, stream>>>(values, fx, BN);

    dim3 sgrid(Kused, BATCH);
    const int BN4 = BN / 4;
    // Phase 1: gather fx at src (row 0), scatter to tgt (row 1)
    scatter_lds_kernel<<<sgrid, STB, 0, stream>>>(fx, weights, edge_ix, partial,
                                                  E, N, chunk, 0L, (long)E);
    reduce_pred_err_kernel<<<(BN4 + TB - 1) / TB, TB, 0, stream>>>(
        (const float4*)partial, (const float4*)values,
        (float4*)pred, (float4*)err, BN4, Kused);

    // Phase 2: gather err at tgt (row 1), scatter to src (row 0)
    scatter_lds_kernel<<<sgrid, STB, 0, stream>>>(err, weights, edge_ix, partial,
                                                  E, N, chunk, (long)E, 0L);
    reduce_dx_kernel<<<(BN4 + TB - 1) / TB, TB, 0, stream>>>(
        (const float4*)partial, (const float4*)fx,
        (const float4*)err, (float4*)dx, BN4, Kused);
}

// Round 4
// 253.952 us; speedup vs baseline: 1.2135x; 1.2135x over previous
//
#include <hip/hip_runtime.h>

#define BATCH 8
#define NN 10000      // nodes per graph
#define STB 1024      // scatter block size (16 waves)
#define TB 256

__global__ void fx_kernel(const float* __restrict__ values,
                          float* __restrict__ fx, int bn) {
    int i = blockIdx.x * blockDim.x + threadIdx.x;
    if (i < bn) fx[i] = tanhf(values[i]);
}

// One block = (edge-chunk k, batch b). Stage the batch's gather slice into
// LDS, accumulate w[e]*g_lds[gi] into an LDS accumulator over all N nodes,
// flush partial sums coalesced. No global atomics, no global gathers.
// partial layout: partial[(k*BATCH+b)*N + i]. chunk % 4 == 0.
__global__ __launch_bounds__(STB, 8) void scatter_lds_kernel(
        const float* __restrict__ gsrc,   // gather base [B*N] (fx or err)
        const float* __restrict__ w,      // [E]
        const int* __restrict__ idx,      // [2,E]
        float* __restrict__ partial,
        int E, int N, int chunk,
        long gather_off, long scatter_off)
{
    __shared__ float acc[NN];
    __shared__ float fxs[NN];

    const int k = blockIdx.x, b = blockIdx.y;
    const float* __restrict__ g = gsrc + (long)b * N;

    // zero acc + stage gather slice (vectorized, coalesced)
    int n4 = N >> 2;
    float4* acc4 = (float4*)acc;
    float4* fxs4 = (float4*)fxs;
    const float4* g4 = (const float4*)g;
    for (int i = threadIdx.x; i < n4; i += STB) {
        acc4[i] = make_float4(0.f, 0.f, 0.f, 0.f);
        fxs4[i] = g4[i];
    }
    for (int i = (n4 << 2) + threadIdx.x; i < N; i += STB) {
        acc[i] = 0.f;
        fxs[i] = g[i];
    }
    __syncthreads();

    long e0 = (long)k * chunk;
    long e1 = e0 + chunk;
    if (e1 > E) e1 = E;
    long n = e1 - e0;
    long nvec = n >> 2;

    const int*   gip = idx + gather_off + e0;
    const int*   sip = idx + scatter_off + e0;
    const float* wp  = w + e0;

    for (long v = threadIdx.x; v < nvec; v += STB) {
        int4   gi = ((const int4*)gip)[v];
        int4   si = ((const int4*)sip)[v];
        float4 wv = ((const float4*)wp)[v];
        // 4 independent LDS-gather + LDS-atomic chains
        float m0 = wv.x * fxs[gi.x];
        float m1 = wv.y * fxs[gi.y];
        float m2 = wv.z * fxs[gi.z];
        float m3 = wv.w * fxs[gi.w];
        atomicAdd(&acc[si.x], m0);
        atomicAdd(&acc[si.y], m1);
        atomicAdd(&acc[si.z], m2);
        atomicAdd(&acc[si.w], m3);
    }
    for (long e = (nvec << 2) + threadIdx.x; e < n; e += STB) {
        atomicAdd(&acc[sip[e]], wp[e] * fxs[gip[e]]);
    }
    __syncthreads();

    float* __restrict__ p = partial + ((long)k * BATCH + b) * N;
    float4* p4 = (float4*)p;
    for (int i = threadIdx.x; i < n4; i += STB) p4[i] = acc4[i];
    for (int i = (n4 << 2) + threadIdx.x; i < N; i += STB) p[i] = acc[i];
}

// block: (32 j-float4's) x (8 k-slices); LDS tree over k-slices.
__global__ void reduce_pred_err_kernel(const float4* __restrict__ partial,
                                       const float4* __restrict__ values,
                                       float4* __restrict__ pred,
                                       float4* __restrict__ err,
                                       int BN4, int K) {
    __shared__ float4 sm[8][32];
    int j = blockIdx.x * 32 + threadIdx.x;
    float4 s = make_float4(0.f, 0.f, 0.f, 0.f);
    if (j < BN4) {
        for (int k = threadIdx.y; k < K; k += 8) {
            float4 p = partial[(long)k * BN4 + j];
            s.x += p.x; s.y += p.y; s.z += p.z; s.w += p.w;
        }
    }
    sm[threadIdx.y][threadIdx.x] = s;
    __syncthreads();
    if (threadIdx.y == 0 && j < BN4) {
        float4 t = sm[0][threadIdx.x];
#pragma unroll
        for (int r = 1; r < 8; ++r) {
            float4 p = sm[r][threadIdx.x];
            t.x += p.x; t.y += p.y; t.z += p.z; t.w += p.w;
        }
        pred[j] = t;
        float4 v = values[j];
        err[j] = make_float4(v.x - t.x, v.y - t.y, v.z - t.z, v.w - t.w);
    }
}

__global__ void reduce_dx_kernel(const float4* __restrict__ partial,
                                 const float4* __restrict__ fx,
                                 const float4* __restrict__ err,
                                 float4* __restrict__ dx,
                                 int BN4, int K) {
    __shared__ float4 sm[8][32];
    int j = blockIdx.x * 32 + threadIdx.x;
    float4 s = make_float4(0.f, 0.f, 0.f, 0.f);
    if (j < BN4) {
        for (int k = threadIdx.y; k < K; k += 8) {
            float4 p = partial[(long)k * BN4 + j];
            s.x += p.x; s.y += p.y; s.z += p.z; s.w += p.w;
        }
    }
    sm[threadIdx.y][threadIdx.x] = s;
    __syncthreads();
    if (threadIdx.y == 0 && j < BN4) {
        float4 t = sm[0][threadIdx.x];
#pragma unroll
        for (int r = 1; r < 8; ++r) {
            float4 p = sm[r][threadIdx.x];
            t.x += p.x; t.y += p.y; t.z += p.z; t.w += p.w;
        }
        float4 f = fx[j];
        float4 e = err[j];
        dx[j] = make_float4(e.x - (1.0f - f.x * f.x) * t.x,
                            e.y - (1.0f - f.y * f.y) * t.y,
                            e.z - (1.0f - f.z * f.z) * t.z,
                            e.w - (1.0f - f.w * f.w) * t.w);
    }
}

extern "C" void kernel_launch(void* const* d_in, const int* in_sizes, int n_in,
                              void* d_out, int out_size, void* d_ws, size_t ws_size,
                              hipStream_t stream) {
    const float* values  = (const float*)d_in[0];   // [B*N]
    const float* weights = (const float*)d_in[1];   // [E]
    const int*   edge_ix = (const int*)d_in[2];     // [2, E]

    const int BN = in_sizes[0];        // 80000
    const int E  = in_sizes[1];        // 2,000,000
    const int N  = BN / BATCH;         // 10000

    float* out  = (float*)d_out;       // [3, B*N]
    float* pred = out;
    float* err  = out + BN;
    float* dx   = out + 2 * BN;

    float* fx      = (float*)d_ws;               // BN floats
    float* partial = fx + BN;                    // K*BN floats

    // K=64 -> 512 scatter blocks = exactly 2/CU (the LDS-limited residency).
    size_t fx_bytes = (size_t)BN * sizeof(float);
    int K = 64;
    while (K > 8 && fx_bytes + (size_t)K * BN * sizeof(float) > ws_size) K >>= 1;
    int chunk = (((E + K - 1) / K) + 3) & ~3;
    int Kused = (E + chunk - 1) / chunk;

    fx_kernel<<<(BN + TB - 1) / TB, TB, 0, stream>>>(values, fx, BN);

    dim3 sgrid(Kused, BATCH);
    const int BN4 = BN / 4;
    dim3 rblock(32, 8);
    dim3 rgrid((BN4 + 31) / 32);

    // Phase 1: gather fx at src (row 0), scatter to tgt (row 1)
    scatter_lds_kernel<<<sgrid, STB, 0, stream>>>(fx, weights, edge_ix, partial,
                                                  E, N, chunk, 0L, (long)E);
    reduce_pred_err_kernel<<<rgrid, rblock, 0, stream>>>(
        (const float4*)partial, (const float4*)values,
        (float4*)pred, (float4*)err, BN4, Kused);

    // Phase 2: gather err at tgt (row 1), scatter to src (row 0)
    scatter_lds_kernel<<<sgrid, STB, 0, stream>>>(err, weights, edge_ix, partial,
                                                  E, N, chunk, (long)E, 0L);
    reduce_dx_kernel<<<rgrid, rblock, 0, stream>>>(
        (const float4*)partial, (const float4*)fx,
        (const float4*)err, (float4*)dx, BN4, Kused);
}